// Round 1
// 515.893 us; speedup vs baseline: 1.1368x; 1.1368x over previous
//
#include <hip/hip_runtime.h>

#define SEQ 512
#define FEAT 64
#define HID 32
#define NCLS 10
#define BATCH 2048
#define GRP 8              // timesteps staged per group
#define NGRP (SEQ / GRP)   // 64 groups

// ---------------------------------------------------------------------------
// Fully fused RNN: input projection + recurrence + FC head in ONE kernel.
// 1 wave per block, 2 batches per wave (lane halves), lane = h index.
//   - W_ih row (64f) and W_hh row (32f) in VGPRs per lane.
//   - x streamed 8 steps ahead: global->regs->LDS double buffer.
//   - Per step: rec FMAs -> tanh -> ds_write h -> [x reads + 64 proj FMAs
//     for t+8 fill the LDS write->read bubble] -> h broadcast reload.
// No __syncthreads needed: 1 wave/block, DS pipe is in-order per wave.
// ---------------------------------------------------------------------------
__device__ __forceinline__ float tanh_fast(float v) {
    float e = __expf(-2.f * v);
    return (1.f - e) * __frcp_rn(1.f + e);
}

__global__ __launch_bounds__(64) void rnn_fused(
    const float* __restrict__ x,     // [B, S, F]
    const float* __restrict__ W_ih,  // [H, F]
    const float* __restrict__ W_hh,  // [H, H]
    const float* __restrict__ b_ih,  // [H]
    const float* __restrict__ b_hh,  // [H]
    const float* __restrict__ fc_W,  // [NCLS, H]
    const float* __restrict__ fc_b,  // [NCLS]
    float* __restrict__ out)         // [B, NCLS]
{
    __shared__ float xs[2][2][GRP * FEAT];  // [parity][batch][8 rows x 64 f] = 8 KB
    __shared__ float hl[64];                // h broadcast (2 halves x 32)

    const int l    = threadIdx.x;
    const int j    = l & 31;    // h index
    const int half = l >> 5;    // which batch of the pair
    const int b0   = blockIdx.x * 2;

    // weights to registers (per-lane rows)
    float4 wih[16];
#pragma unroll
    for (int k = 0; k < 16; k++) wih[k] = *(const float4*)&W_ih[j * FEAT + k * 4];
    float4 whh[8];
#pragma unroll
    for (int k = 0; k < 8; k++) whh[k] = *(const float4*)&W_hh[j * HID + k * 4];
    const float bias = b_ih[j] + b_hh[j];

    const float4* xg0 = (const float4*)(x + (size_t)b0 * SEQ * FEAT);
    const float4* xg1 = xg0 + (SEQ * FEAT / 4);

    float4 ld0, ld1, ld2, ld3;  // one group (8 rows) x 2 batches in flight

    auto loadg = [&](int g) {   // coalesced: 64 lanes x 16B = 4 rows per instr
        ld0 = xg0[128 * g + l];
        ld1 = xg0[128 * g + l + 64];
        ld2 = xg1[128 * g + l];
        ld3 = xg1[128 * g + l + 64];
    };
    auto stores = [&](int p) {  // contiguous b128 writes: conflict-free
        *(float4*)&xs[p][0][4 * l]        = ld0;
        *(float4*)&xs[p][0][4 * (l + 64)] = ld1;
        *(float4*)&xs[p][1][4 * l]        = ld2;
        *(float4*)&xs[p][1][4 * (l + 64)] = ld3;
    };
    // xw[b][t][j] = x[b][t][:] . W_ih[j][:] + bias   (reads are half-wide
    // broadcasts: 2 addresses per ds_read_b128 -> 2-way -> free)
    auto dot64 = [&](int p, int s) -> float {
        const float* xr = &xs[p][half][s * 64];
        float a0 = bias, a1 = 0.f, a2 = 0.f, a3 = 0.f;
#pragma unroll
        for (int f4 = 0; f4 < 16; f4++) {
            float4 xv = *(const float4*)&xr[f4 * 4];
            a0 = fmaf(xv.x, wih[f4].x, a0);
            a1 = fmaf(xv.y, wih[f4].y, a1);
            a2 = fmaf(xv.z, wih[f4].z, a2);
            a3 = fmaf(xv.w, wih[f4].w, a3);
        }
        return (a0 + a1) + (a2 + a3);
    };

    // ---- prologue: stage groups 0,1; hold group 2 in regs; project group 0
    loadg(0); stores(0);
    loadg(1); stores(1);
    loadg(2);

    float xwc[8], xwn[8];
#pragma unroll
    for (int s = 0; s < 8; s++) xwc[s] = dot64(0, s);

    float h[HID];
#pragma unroll
    for (int k = 0; k < HID; k++) h[k] = 0.f;

    // ---- main loop: group g consumes xwc (proj of group g), builds xwn from
    // x(g+1) in LDS, writes x(g+2) from regs, prefetches x(g+3) from HBM.
#pragma unroll 1
    for (int g = 0; g < NGRP; g++) {
        if (g < NGRP - 2) stores(g & 1);   // x(g+2) -> xs[(g+2)&1], old data dead
        if (g < NGRP - 3) loadg(g + 3);    // HBM latency hides under 8 steps
        const int pn = (g + 1) & 1;
#pragma unroll
        for (int s = 0; s < 8; s++) {
            // recurrence: a = xw_t + W_hh[j][:] . h[:]
            float a0 = xwc[s], a1 = 0.f, a2 = 0.f, a3 = 0.f;
#pragma unroll
            for (int k4 = 0; k4 < 8; k4++) {
                a0 = fmaf(whh[k4].x, h[4 * k4 + 0], a0);
                a1 = fmaf(whh[k4].y, h[4 * k4 + 1], a1);
                a2 = fmaf(whh[k4].z, h[4 * k4 + 2], a2);
                a3 = fmaf(whh[k4].w, h[4 * k4 + 3], a3);
            }
            float hn = tanh_fast((a0 + a1) + (a2 + a3));
            hl[l] = hn;
            // projection for step t+8 fills the LDS write->read bubble
            if (g < NGRP - 1) xwn[s] = dot64(pn, s);
            // h broadcast reload (uniform per half -> broadcast reads)
#pragma unroll
            for (int k4 = 0; k4 < 8; k4++) {
                float4 hv = *(const float4*)&hl[half * 32 + 4 * k4];
                h[4 * k4 + 0] = hv.x; h[4 * k4 + 1] = hv.y;
                h[4 * k4 + 2] = hv.z; h[4 * k4 + 3] = hv.w;
            }
        }
#pragma unroll
        for (int s = 0; s < 8; s++) xwc[s] = xwn[s];
    }

    // ---- FC head: every lane already holds the full final h of its batch
    if (j < NCLS) {
        const float* fw = fc_W + j * HID;
        float s0 = fc_b[j], s1 = 0.f;
#pragma unroll
        for (int k = 0; k < HID; k += 2) {
            s0 = fmaf(fw[k],     h[k],     s0);
            s1 = fmaf(fw[k + 1], h[k + 1], s1);
        }
        out[(size_t)(b0 + half) * NCLS + j] = s0 + s1;
    }
}

extern "C" void kernel_launch(void* const* d_in, const int* in_sizes, int n_in,
                              void* d_out, int out_size, void* d_ws, size_t ws_size,
                              hipStream_t stream) {
    const float* x    = (const float*)d_in[0];
    const float* W_ih = (const float*)d_in[1];
    const float* W_hh = (const float*)d_in[2];
    const float* b_ih = (const float*)d_in[3];
    const float* b_hh = (const float*)d_in[4];
    const float* fc_W = (const float*)d_in[5];
    const float* fc_b = (const float*)d_in[6];
    float* out = (float*)d_out;

    rnn_fused<<<BATCH / 2, 64, 0, stream>>>(x, W_ih, W_hh, b_ih, b_hh,
                                            fc_W, fc_b, out);
}

// Round 3
// 483.545 us; speedup vs baseline: 1.2129x; 1.0669x over previous
//
#include <hip/hip_runtime.h>

#define SEQ 512
#define FEAT 64
#define HID 32
#define NCLS 10
#define BATCH 2048
#define GRP 8              // timesteps staged per group
#define NGRP (SEQ / GRP)   // 64 groups

// ---------------------------------------------------------------------------
// Fused RNN, k-split layout: ONE batch per wave -> 2048 waves = 2 per SIMD.
// Lane l: j = l&31 (output h index), kh = l>>5 (reduction half).
//   - lane regs: W_ih[j][32kh..+32) (8xfloat4), W_hh[j][16kh..+16) (4xfloat4),
//     h[16] = h_state[16kh..+16).
//   - per step: rec partial (16 FMA) + proj partial for t+8 (32 FMA, 8 LDS
//     broadcast reads); halves combined with __builtin_amdgcn_permlane32_swap
//     (VALU pipe, compiler-managed hazards — the round-2 raw-asm version hit
//     the permlane read-after-VALU-write hazard and returned stale data).
//   - x streamed global->regs->LDS double buffer, 1 group (8 rows) ahead.
// DS per wave-step: 13 instrs; 2 waves/SIMD hide LDS round-trip + tanh
// latency. No __syncthreads: 1 wave/block, DS pipe in-order per wave.
// ---------------------------------------------------------------------------
__device__ __forceinline__ float tanh_fast(float v) {
    float e = __expf(-2.f * v);
    return (1.f - e) * __frcp_rn(1.f + e);
}

// Full cross-half sum: every lane returns p[lane&31] + p[(lane&31)+32].
// permlane32_swap(p, p) yields {lo-half broadcast, hi-half broadcast} in some
// order; summing both words is direction-agnostic and identical in all lanes.
__device__ __forceinline__ float half_swap_add(float p) {
    typedef unsigned uv2 __attribute__((ext_vector_type(2)));
    unsigned pu = __float_as_uint(p);
    uv2 r = __builtin_amdgcn_permlane32_swap(pu, pu, false, false);
    return __uint_as_float(r.x) + __uint_as_float(r.y);
}

__global__ __launch_bounds__(64) void rnn_fused(
    const float* __restrict__ x,     // [B, S, F]
    const float* __restrict__ W_ih,  // [H, F]
    const float* __restrict__ W_hh,  // [H, H]
    const float* __restrict__ b_ih,  // [H]
    const float* __restrict__ b_hh,  // [H]
    const float* __restrict__ fc_W,  // [NCLS, H]
    const float* __restrict__ fc_b,  // [NCLS]
    float* __restrict__ out)         // [B, NCLS]
{
    __shared__ float xs[2][GRP * FEAT];  // 4 KB: 2 x (8 rows x 64 f)
    __shared__ float hl[64];             // h broadcast (both kh copies)

    const int l  = threadIdx.x;
    const int j  = l & 31;   // h index
    const int kh = l >> 5;   // reduction half
    const int b  = blockIdx.x;

    // per-lane weight halves
    float4 wih[8];
#pragma unroll
    for (int k = 0; k < 8; k++)
        wih[k] = *(const float4*)&W_ih[j * FEAT + 32 * kh + 4 * k];
    float4 whh[4];
#pragma unroll
    for (int k = 0; k < 4; k++)
        whh[k] = *(const float4*)&W_hh[j * HID + 16 * kh + 4 * k];
    const float pbias = (kh == 0) ? (b_ih[j] + b_hh[j]) : 0.f;  // counted once

    const float4* xg = (const float4*)(x + (size_t)b * SEQ * FEAT);
    float4 ld0, ld1;  // one group (8 rows x 64 f = 128 float4) in flight

    auto loadg = [&](int g) {  // coalesced: 64 lanes x 16B
        ld0 = xg[128 * g + l];
        ld1 = xg[128 * g + 64 + l];
    };
    auto stores = [&](int p) {  // contiguous b128 writes
        *(float4*)&xs[p][4 * l]        = ld0;
        *(float4*)&xs[p][4 * (l + 64)] = ld1;
    };
    // proj partial over this lane's f-half: 8 broadcast b128 reads + 32 FMA.
    // two address groups per read (kh halves) = 2-way = free.
    auto dot32 = [&](int p, int s) -> float {
        const float* xr = &xs[p][s * 64 + 32 * kh];
        float a0 = pbias, a1 = 0.f, a2 = 0.f, a3 = 0.f;
#pragma unroll
        for (int f4 = 0; f4 < 8; f4++) {
            float4 xv = *(const float4*)&xr[f4 * 4];
            a0 = fmaf(xv.x, wih[f4].x, a0);
            a1 = fmaf(xv.y, wih[f4].y, a1);
            a2 = fmaf(xv.z, wih[f4].z, a2);
            a3 = fmaf(xv.w, wih[f4].w, a3);
        }
        return (a0 + a1) + (a2 + a3);
    };

    // ---- prologue: stage groups 0,1; hold group 2 in regs; project group 0
    loadg(0); stores(0);
    loadg(1); stores(1);
    loadg(2);

    float xwc[8], xwn[8];
#pragma unroll
    for (int s = 0; s < 8; s++) xwc[s] = dot32(0, s);

    float h[16];  // this lane's k-half of the hidden state
#pragma unroll
    for (int k = 0; k < 16; k++) h[k] = 0.f;

    const int hbase = 48 * kh;  // kh0 reads hl[0..16), kh1 reads hl[48..64)

    // ---- main loop: consume xwc (proj of group g), build xwn from x(g+1),
    // write x(g+2) from regs, prefetch x(g+3) from HBM.
#pragma unroll 1
    for (int g = 0; g < NGRP; g++) {
        if (g < NGRP - 2) stores(g & 1);   // x(g+2): old xs[g&1] is dead
        if (g < NGRP - 3) loadg(g + 3);    // HBM latency hides under 8 steps
        const int pn = (g + 1) & 1;
#pragma unroll
        for (int s = 0; s < 8; s++) {
            // rec partial over this lane's k-half
            float a0 = xwc[s], a1 = 0.f, a2 = 0.f, a3 = 0.f;
#pragma unroll
            for (int k4 = 0; k4 < 4; k4++) {
                a0 = fmaf(whh[k4].x, h[4 * k4 + 0], a0);
                a1 = fmaf(whh[k4].y, h[4 * k4 + 1], a1);
                a2 = fmaf(whh[k4].z, h[4 * k4 + 2], a2);
                a3 = fmaf(whh[k4].w, h[4 * k4 + 3], a3);
            }
            float partial = (a0 + a1) + (a2 + a3);
            float hn = tanh_fast(half_swap_add(partial));
            hl[l] = hn;                       // both kh copies written
            // proj for step t+8 fills the LDS write->read bubble
            if (g < NGRP - 1) xwn[s] = dot32(pn, s);
            // reload this lane's k-half (broadcast reads, 2 addrs/instr)
#pragma unroll
            for (int k4 = 0; k4 < 4; k4++) {
                float4 hv = *(const float4*)&hl[hbase + 4 * k4];
                h[4 * k4 + 0] = hv.x; h[4 * k4 + 1] = hv.y;
                h[4 * k4 + 2] = hv.z; h[4 * k4 + 3] = hv.w;
            }
        }
#pragma unroll
        for (int s = 0; s < 8; s++) xwc[s] = xwn[s];
    }

    // ---- FC head: lane holds h-half; reduce across kh with the same swap
    float fpart = 0.f;
    if (j < NCLS) {
        const float* fw = fc_W + j * HID + 16 * kh;
        float s0 = 0.f, s1 = 0.f;
#pragma unroll
        for (int k = 0; k < 16; k += 2) {
            s0 = fmaf(fw[k],     h[k],     s0);
            s1 = fmaf(fw[k + 1], h[k + 1], s1);
        }
        fpart = s0 + s1;
    }
    float ftot = half_swap_add(fpart);
    if (j < NCLS && kh == 0)
        out[(size_t)b * NCLS + j] = ftot + fc_b[j];
}

extern "C" void kernel_launch(void* const* d_in, const int* in_sizes, int n_in,
                              void* d_out, int out_size, void* d_ws, size_t ws_size,
                              hipStream_t stream) {
    const float* x    = (const float*)d_in[0];
    const float* W_ih = (const float*)d_in[1];
    const float* W_hh = (const float*)d_in[2];
    const float* b_ih = (const float*)d_in[3];
    const float* b_hh = (const float*)d_in[4];
    const float* fc_W = (const float*)d_in[5];
    const float* fc_b = (const float*)d_in[6];
    float* out = (float*)d_out;

    rnn_fused<<<BATCH, 64, 0, stream>>>(x, W_ih, W_hh, b_ih, b_hh,
                                        fc_W, fc_b, out);
}

// Round 4
// 382.584 us; speedup vs baseline: 1.5330x; 1.2639x over previous
//
#include <hip/hip_runtime.h>
#include <hip/hip_bf16.h>

#define SEQ 512
#define FEAT 64
#define HID 32
#define NCLS 10
#define BATCH 2048
#define SG 16              // timesteps per super-group (MFMA M=16)
#define NSG (SEQ / SG)     // 32
#define XWP 34             // xw_lds row pad: bank groups at 0/8/16/24 -> 2-way max

typedef __attribute__((ext_vector_type(8))) short bf16x8;
typedef __attribute__((ext_vector_type(4))) float f32x4;

// ---------------------------------------------------------------------------
// Fused RNN v4: projection moved to the MFMA pipe.
// 1 batch per wave (2048 waves = 2/SIMD). Lane l: j=l&31 (h index), kh=l>>5
// (rec k-half), r16=l&15 / q=l>>4 (MFMA fragment coords).
// Per 16-step group: x A-frags loaded DIRECTLY from global in fragment order
// (32B/lane contiguous), cast f32->bf16, 4x mfma_f32_16x16x32_bf16 against
// W_ih B-frags (bias folded into acc init), D redistributed to xw_lds
// (8 ds_write_b32, pad-34 conflict-free), consumed as 16 hoisted broadcast
// reads. Recurrence stays exact fp32: 16 FMA k-half partial + permlane32
// swap-add + tanh; h broadcast via hl[64] (1 write + 4 b128 broadcast reads).
// VALU/step ~36 (was ~69), DS/step ~6.5 (was 13), MFMA pipe now carries the
// projection. No __syncthreads: 1 wave/block, DS in-order per wave.
// ---------------------------------------------------------------------------
__device__ __forceinline__ float tanh_fast(float v) {
    float e = __expf(-2.f * v);
    return (1.f - e) * __frcp_rn(1.f + e);
}

// Full cross-half sum via permlane32_swap (VALU pipe, compiler-managed
// hazards). Direction-agnostic: sum both returned words.
__device__ __forceinline__ float half_swap_add(float p) {
    typedef unsigned uv2 __attribute__((ext_vector_type(2)));
    unsigned pu = __float_as_uint(p);
    uv2 r = __builtin_amdgcn_permlane32_swap(pu, pu, false, false);
    return __uint_as_float(r.x) + __uint_as_float(r.y);
}

__device__ __forceinline__ short bf16b(float f) {
    __hip_bfloat16 h = __float2bfloat16(f);
    return *(short*)&h;
}

__global__ __launch_bounds__(64) void rnn_fused(
    const float* __restrict__ x,     // [B, S, F]
    const float* __restrict__ W_ih,  // [H, F]
    const float* __restrict__ W_hh,  // [H, H]
    const float* __restrict__ b_ih,  // [H]
    const float* __restrict__ b_hh,  // [H]
    const float* __restrict__ fc_W,  // [NCLS, H]
    const float* __restrict__ fc_b,  // [NCLS]
    float* __restrict__ out)         // [B, NCLS]
{
    __shared__ float xw_lds[SG * XWP];  // [16 t][34] padded, 2176 B
    __shared__ float hl[64];            // h broadcast (both kh copies)

    const int l   = threadIdx.x;
    const int j   = l & 31;   // h index
    const int kh  = l >> 5;   // rec reduction half
    const int r16 = l & 15;   // MFMA: A row (=t within group) / D col (=j&15)
    const int q   = l >> 4;   // MFMA: k-block 0..3
    const int b   = blockIdx.x;

    // ---- B fragments: bw[nh][c][i] = W_ih[nh*16+r16][c*32+q*8+i] (bf16).
    // A and B use the same lane->k map, so any k-permutation cancels.
    bf16x8 bw00, bw01, bw10, bw11;
    {
        const float* w00 = &W_ih[(r16)      * FEAT + q * 8];
        const float* w01 = &W_ih[(r16)      * FEAT + 32 + q * 8];
        const float* w10 = &W_ih[(16 + r16) * FEAT + q * 8];
        const float* w11 = &W_ih[(16 + r16) * FEAT + 32 + q * 8];
#pragma unroll
        for (int i = 0; i < 8; i++) {
            bw00[i] = bf16b(w00[i]);
            bw01[i] = bf16b(w01[i]);
            bw10[i] = bf16b(w10[i]);
            bw11[i] = bf16b(w11[i]);
        }
    }
    // bias folded into MFMA accumulator init (D col = lane&15 = j&15)
    const float bias0 = b_ih[r16]      + b_hh[r16];
    const float bias1 = b_ih[16 + r16] + b_hh[16 + r16];

    // rec weights: this lane's k-half of W_hh row j
    float4 whh[4];
#pragma unroll
    for (int k = 0; k < 4; k++)
        whh[k] = *(const float4*)&W_hh[j * HID + 16 * kh + 4 * k];

    // x fragment base: lane covers rows r16(+16t), f = c*32 + q*8 .. +8
    const float* xbase = x + (size_t)b * SEQ * FEAT + r16 * FEAT + q * 8;

    // project one group's x (held in 4 float4 regs) -> xw_lds
    auto proj = [&](float4 p0, float4 p1, float4 p2, float4 p3) {
        bf16x8 a0v, a1v;  // A-frags for K-chunks 0,1
        a0v[0] = bf16b(p0.x); a0v[1] = bf16b(p0.y);
        a0v[2] = bf16b(p0.z); a0v[3] = bf16b(p0.w);
        a0v[4] = bf16b(p1.x); a0v[5] = bf16b(p1.y);
        a0v[6] = bf16b(p1.z); a0v[7] = bf16b(p1.w);
        a1v[0] = bf16b(p2.x); a1v[1] = bf16b(p2.y);
        a1v[2] = bf16b(p2.z); a1v[3] = bf16b(p2.w);
        a1v[4] = bf16b(p3.x); a1v[5] = bf16b(p3.y);
        a1v[6] = bf16b(p3.z); a1v[7] = bf16b(p3.w);
        f32x4 ac0 = {bias0, bias0, bias0, bias0};
        f32x4 ac1 = {bias1, bias1, bias1, bias1};
        ac0 = __builtin_amdgcn_mfma_f32_16x16x32_bf16(a0v, bw00, ac0, 0, 0, 0);
        ac0 = __builtin_amdgcn_mfma_f32_16x16x32_bf16(a1v, bw01, ac0, 0, 0, 0);
        ac1 = __builtin_amdgcn_mfma_f32_16x16x32_bf16(a0v, bw10, ac1, 0, 0, 0);
        ac1 = __builtin_amdgcn_mfma_f32_16x16x32_bf16(a1v, bw11, ac1, 0, 0, 0);
        // D: col=lane&15, row=(lane>>4)*4+r  (verified m89/m91)
#pragma unroll
        for (int r = 0; r < 4; r++) {
            xw_lds[(q * 4 + r) * XWP + r16]      = ac0[r];
            xw_lds[(q * 4 + r) * XWP + 16 + r16] = ac1[r];
        }
    };

    // ---- prologue: proj group 0; leave group 1 in rawC
    float4 rawC[4], rawN[4];
#pragma unroll
    for (int c = 0; c < 2; c++) {
        rawC[c * 2]     = *(const float4*)(xbase + c * 32);
        rawC[c * 2 + 1] = *(const float4*)(xbase + c * 32 + 4);
    }
    proj(rawC[0], rawC[1], rawC[2], rawC[3]);
#pragma unroll
    for (int c = 0; c < 2; c++) {
        rawC[c * 2]     = *(const float4*)(xbase + SG * FEAT + c * 32);
        rawC[c * 2 + 1] = *(const float4*)(xbase + SG * FEAT + c * 32 + 4);
    }
#pragma unroll
    for (int i = 0; i < 4; i++) rawN[i] = rawC[i];

    float h[16];
#pragma unroll
    for (int k = 0; k < 16; k++) h[k] = 0.f;
    const int hbase = 48 * kh;  // kh0: hl[0..16), kh1: hl[48..64) (duplicate)

    // ---- main loop over 32 super-groups
#pragma unroll 1
    for (int g = 0; g < NSG; g++) {
        // 1) hoist group-g xw (written by proj in body g-1 / prologue)
        float xw16[SG];
#pragma unroll
        for (int s = 0; s < SG; s++) xw16[s] = xw_lds[s * XWP + j];
        // 2) prefetch x frags for group g+2 (latency budget: 16 steps)
        if (g + 2 < NSG) {
            const float* xp = xbase + (size_t)(g + 2) * SG * FEAT;
#pragma unroll
            for (int c = 0; c < 2; c++) {
                rawN[c * 2]     = *(const float4*)(xp + c * 32);
                rawN[c * 2 + 1] = *(const float4*)(xp + c * 32 + 4);
            }
        }
        // 3) MFMA-project group g+1 (writes queue after step-1 reads; DS
        //    in-order per wave -> no race on the single xw_lds buffer)
        if (g + 1 < NSG) proj(rawC[0], rawC[1], rawC[2], rawC[3]);

        // 4) 16 recurrence steps (exact fp32)
#pragma unroll
        for (int s = 0; s < SG; s++) {
            float a0 = 0.f, a1 = 0.f, a2 = 0.f, a3 = 0.f;
#pragma unroll
            for (int k4 = 0; k4 < 4; k4++) {
                a0 = fmaf(whh[k4].x, h[4 * k4 + 0], a0);
                a1 = fmaf(whh[k4].y, h[4 * k4 + 1], a1);
                a2 = fmaf(whh[k4].z, h[4 * k4 + 2], a2);
                a3 = fmaf(whh[k4].w, h[4 * k4 + 3], a3);
            }
            float rec = (a0 + a1) + (a2 + a3);
            float hn  = tanh_fast(half_swap_add(rec) + xw16[s]);
            hl[l] = hn;
            // reload this lane's k-half (broadcast b128 reads)
#pragma unroll
            for (int k4 = 0; k4 < 4; k4++) {
                float4 hv = *(const float4*)&hl[hbase + 4 * k4];
                h[4 * k4 + 0] = hv.x; h[4 * k4 + 1] = hv.y;
                h[4 * k4 + 2] = hv.z; h[4 * k4 + 3] = hv.w;
            }
        }
        // 5) rotate prefetch buffer
#pragma unroll
        for (int i = 0; i < 4; i++) rawC[i] = rawN[i];
    }

    // ---- FC head: lane holds h k-half; reduce across kh with the same swap
    float fpart = 0.f;
    if (j < NCLS) {
        const float* fw = fc_W + j * HID + 16 * kh;
        float s0 = 0.f, s1 = 0.f;
#pragma unroll
        for (int k = 0; k < 16; k += 2) {
            s0 = fmaf(fw[k],     h[k],     s0);
            s1 = fmaf(fw[k + 1], h[k + 1], s1);
        }
        fpart = s0 + s1;
    }
    float ftot = half_swap_add(fpart);
    if (j < NCLS && kh == 0)
        out[(size_t)b * NCLS + j] = ftot + fc_b[j];
}

extern "C" void kernel_launch(void* const* d_in, const int* in_sizes, int n_in,
                              void* d_out, int out_size, void* d_ws, size_t ws_size,
                              hipStream_t stream) {
    const float* x    = (const float*)d_in[0];
    const float* W_ih = (const float*)d_in[1];
    const float* W_hh = (const float*)d_in[2];
    const float* b_ih = (const float*)d_in[3];
    const float* b_hh = (const float*)d_in[4];
    const float* fc_W = (const float*)d_in[5];
    const float* fc_b = (const float*)d_in[6];
    float* out = (float*)d_out;

    rnn_fused<<<BATCH, 64, 0, stream>>>(x, W_ih, W_hh, b_ih, b_hh,
                                        fc_W, fc_b, out);
}